// Round 9
// baseline (32.715 us; speedup 1.0000x reference)
//
#include <hip/hip_runtime.h>

#define BATCH  8
#define NPTS   4096
#define NSLICE 32                 // target-set split per (dir,b)
#define SLICE  (NPTS / NSLICE)    // 128 targets per block
#define TPB1   512                // 8 waves/block, 2 blocks/CU -> 4 waves/SIMD
#define QPT    8                  // queries per thread (4096 / 512)

// Stage 1: grid = 2 dirs x 8 batches x 32 target-slices = 512 blocks.
// Proven skeleton: 8 named-scalar queries/thread, 128-target slice in LDS
// as (-2y,||y||^2), 2 targets/iter with v_min3_f32 fusion (3.5 instr/pair),
// plain coalesced partial-min stores (no device atomics).
// Round-9 delta: NSLICE 16->32 + __launch_bounds__(512,4) raises occupancy
// from 2 to 4 waves/SIMD to hide dependent-min3/LDS latency.
__global__ __launch_bounds__(TPB1, 4) void chamfer_stage1(
    const float* __restrict__ preds,
    const float* __restrict__ gts,
    float* __restrict__ part,     // [16 db][NSLICE][NPTS]
    float* __restrict__ out)
{
    const int blk   = blockIdx.x;
    const int slice = blk % NSLICE;
    const int db    = blk / NSLICE;    // dir*8 + b
    const int dir   = db >> 3;
    const int b     = db & 7;

    if (blk == 0 && threadIdx.x == 0) out[0] = 0.0f;

    const float* Q = dir ? gts   : preds;   // query set
    const float* T = dir ? preds : gts;     // target set

    __shared__ float4 sT[SLICE];            // 2 KiB

    const float* Tb = T + ((size_t)b * NPTS + slice * SLICE) * 3;
    if (threadIdx.x < SLICE) {
        const int j = threadIdx.x;
        const float y0 = Tb[j * 3 + 0];
        const float y1 = Tb[j * 3 + 1];
        const float y2 = Tb[j * 3 + 2];
        sT[j] = make_float4(-2.0f * y0, -2.0f * y1, -2.0f * y2,
                            y0 * y0 + y1 * y1 + y2 * y2);
    }

    // This thread's 8 consecutive queries (24 floats = 6 float4).
    const int q0 = threadIdx.x * QPT;
    const float4* p4 = reinterpret_cast<const float4*>(
        Q + ((size_t)b * NPTS + q0) * 3);
    const float4 v0 = p4[0], v1 = p4[1], v2 = p4[2];
    const float4 v3 = p4[3], v4 = p4[4], v5 = p4[5];

    const float qx0 = v0.x, qy0 = v0.y, qz0 = v0.z;
    const float qx1 = v0.w, qy1 = v1.x, qz1 = v1.y;
    const float qx2 = v1.z, qy2 = v1.w, qz2 = v2.x;
    const float qx3 = v2.y, qy3 = v2.z, qz3 = v2.w;
    const float qx4 = v3.x, qy4 = v3.y, qz4 = v3.z;
    const float qx5 = v3.w, qy5 = v4.x, qz5 = v4.y;
    const float qx6 = v4.z, qy6 = v4.w, qz6 = v5.x;
    const float qx7 = v5.y, qy7 = v5.z, qz7 = v5.w;

    __syncthreads();

    float m0 = 3.4e38f, m1 = 3.4e38f, m2 = 3.4e38f, m3 = 3.4e38f;
    float m4 = 3.4e38f, m5 = 3.4e38f, m6 = 3.4e38f, m7 = 3.4e38f;

    // e = ||y||^2 - 2*dot(q,y)  (= ||q-y||^2 - ||q||^2; rx added in stage 2)
    // Two targets per iter; fminf(m, fminf(ea,eb)) fuses to v_min3_f32.
    #define DO_Q2(k) { \
        const float ea = fmaf(qx##k, ya.x, fmaf(qy##k, ya.y, \
                              fmaf(qz##k, ya.z, ya.w))); \
        const float eb = fmaf(qx##k, yb.x, fmaf(qy##k, yb.y, \
                              fmaf(qz##k, yb.z, yb.w))); \
        m##k = fminf(m##k, fminf(ea, eb)); }

    #pragma unroll 4
    for (int j = 0; j < SLICE; j += 2) {
        const float4 ya = sT[j];
        const float4 yb = sT[j + 1];
        DO_Q2(0) DO_Q2(1) DO_Q2(2) DO_Q2(3)
        DO_Q2(4) DO_Q2(5) DO_Q2(6) DO_Q2(7)
    }
    #undef DO_Q2

    // Coalesced 32 B/thread store: part[db][slice][q0..q0+7]
    float4* b4 = reinterpret_cast<float4*>(
        part + ((size_t)db * NSLICE + slice) * NPTS + q0);
    b4[0] = make_float4(m0, m1, m2, m3);
    b4[1] = make_float4(m4, m5, m6, m7);
}

// Stage 2: 4 queries per thread via float4 loads; min over the 32
// slice-partials (16B-coalesced strided loads), add rx, block-reduce,
// one atomicAdd per block (64 blocks total).
#define TPB2 256
#define QP2  4
__global__ __launch_bounds__(TPB2) void chamfer_stage2(
    const float* __restrict__ preds,
    const float* __restrict__ gts,
    const float* __restrict__ part,
    float* __restrict__ out)
{
    const int g   = blockIdx.x * TPB2 + threadIdx.x;   // [0, 2*8*1024)
    const int db  = g >> 10;                           // 1024 thread-groups/db
    const int qq  = (g & 1023) * QP2;                  // query base
    const int dir = db >> 3;
    const int bb  = db & 7;

    const float* pp = part + (size_t)db * NSLICE * NPTS + qq;
    float4 m = make_float4(3.4e38f, 3.4e38f, 3.4e38f, 3.4e38f);
    #pragma unroll 8
    for (int s = 0; s < NSLICE; ++s) {
        const float4 p = *reinterpret_cast<const float4*>(pp + (size_t)s * NPTS);
        m.x = fminf(m.x, p.x); m.y = fminf(m.y, p.y);
        m.z = fminf(m.z, p.z); m.w = fminf(m.w, p.w);
    }

    const float* Q = dir ? gts : preds;
    const float4* q4 = reinterpret_cast<const float4*>(
        Q + ((size_t)bb * NPTS + qq) * 3);
    const float4 a = q4[0], c = q4[1], d = q4[2];   // 12 floats = 4 queries
    const float rx0 = a.x * a.x + a.y * a.y + a.z * a.z;
    const float rx1 = a.w * a.w + c.x * c.x + c.y * c.y;
    const float rx2 = c.z * c.z + c.w * c.w + d.x * d.x;
    const float rx3 = d.y * d.y + d.z * d.z + d.w * d.w;

    float s = (m.x + rx0) + (m.y + rx1) + (m.z + rx2) + (m.w + rx3);

    #pragma unroll
    for (int off = 32; off > 0; off >>= 1)
        s += __shfl_down(s, off, 64);

    __shared__ float red[TPB2 / 64];
    const int lane = threadIdx.x & 63;
    const int wid  = threadIdx.x >> 6;
    if (lane == 0) red[wid] = s;
    __syncthreads();
    if (threadIdx.x == 0) {
        float t = 0.0f;
        #pragma unroll
        for (int w = 0; w < TPB2 / 64; ++w) t += red[w];
        atomicAdd(out, t);
    }
}

extern "C" void kernel_launch(void* const* d_in, const int* in_sizes, int n_in,
                              void* d_out, int out_size, void* d_ws, size_t ws_size,
                              hipStream_t stream) {
    const float* preds = (const float*)d_in[0];
    const float* gts   = (const float*)d_in[1];
    float* out  = (float*)d_out;
    float* part = (float*)d_ws;   // 16 db x 32 slices x 4096 floats = 8 MiB

    // Only 2 dispatches: stage1 zeroes `out` itself; `part` is fully
    // written by stage 1 before stage 2 reads it — no memsets needed.
    chamfer_stage1<<<dim3(2 * BATCH * NSLICE), TPB1, 0, stream>>>(preds, gts, part, out);
    chamfer_stage2<<<dim3(2 * BATCH * NPTS / (TPB2 * QP2)), TPB2, 0, stream>>>(preds, gts, part, out);
}